// Round 8
// baseline (726.724 us; speedup 1.0000x reference)
//
#include <hip/hip_runtime.h>
#include <hip/hip_bf16.h>

// MonetMoVDE: B=4 T=2048 D=2048 H=8 E=512 M=8, F=4096, HALF=1024
#define TOK   8192   // B*T
#define DD    2048
#define FF    4096
#define EE    512
#define HALF  1024
#define KCAT  8704   // F + F + E  (concat K for V-GEMMs, 8704 = 136*64)

typedef __bf16 bf16x8 __attribute__((ext_vector_type(8)));
typedef __bf16 bf16x4 __attribute__((ext_vector_type(4)));
typedef float  f32x4  __attribute__((ext_vector_type(4)));
using bf16 = __hip_bfloat16;

#define AS1(p) ((const __attribute__((address_space(1))) void*)(p))
#define AS3(p) ((__attribute__((address_space(3))) void*)(p))

// ---------------- prep kernels ----------------

__global__ void cvt_bf16(const float* __restrict__ in, bf16* __restrict__ out, int n4) {
    int i = blockIdx.x * blockDim.x + threadIdx.x;
    int stride = gridDim.x * blockDim.x;
    for (; i < n4; i += stride) {
        float4 v = ((const float4*)in)[i];
        bf16x4 o;
        o[0] = (__bf16)v.x; o[1] = (__bf16)v.y; o[2] = (__bf16)v.z; o[3] = (__bf16)v.w;
        ((bf16x4*)out)[i] = o;
    }
}

// W [1024][8704] = [vA | vB | bT]   (vA,vB: [1024][4096] f32; bmat: [512][1024] f32)
__global__ void pack_w(const float* __restrict__ vA, const float* __restrict__ vB,
                       const float* __restrict__ bmat, bf16* __restrict__ W) {
    int n = blockIdx.x;
    const float* ra = vA + (size_t)n * FF;
    const float* rb = vB + (size_t)n * FF;
    bf16* w = W + (size_t)n * KCAT;
    for (int k = threadIdx.x; k < FF; k += 256) {
        w[k]      = __float2bfloat16(ra[k]);
        w[FF + k] = __float2bfloat16(rb[k]);
    }
    for (int e = threadIdx.x; e < EE; e += 256)
        w[2 * FF + e] = __float2bfloat16(bmat[(size_t)e * HALF + n]);
}

// ---------------- GEMM: C[m,n] = sum_k A[m,k] * Bw[n,k] ----------------
// 256x256 tile, BK=64, 8 waves (2Mx4N), 16x16x32 MFMA, per-wave C 128x64.
// LDS buffer (64KB) = 4 planes of 16KB: A_k0 @0, A_k1 @16K, B_k0 @32K, B_k1 @48K.
// Plane = 256 rows x 64B (32 K), swizzle byte ^= (((row>>1)&3)<<4) — zero-conflict
// (verified r2/r5/r6). Double-buffered (2 x 64KB).
// TWO phases per K-tile (one per K-half), ONE barrier each:
//  P0: stage kk0(t+1) (4 loads); vmcnt(4); barrier; read kk1(t) frags (12);
//      32 MFMA on kk0(t) frags (read last phase).
//  P1: stage kk1(t+1) (4 loads); vmcnt(4); barrier; read kk0(t+1) frags (12);
//      32 MFMA on kk1(t) frags.
// Ledger: at each gate outstanding = 8, vmcnt(4) retires exactly the plane the
// post-barrier reads touch. Never drains mid-loop; vmcnt(0) once at tail.
// Two static frag sets alternate by phase parity (no runtime indexing).
// Fused dual-GEMM; MODE 0: fp32 store, MODE 1: relu(z+bias)^2 -> bf16 store.
template<int MODE>
__global__ __launch_bounds__(512, 2)
void gemmR(const bf16* __restrict__ A0, const bf16* __restrict__ B0,
           const float* __restrict__ bias0, void* __restrict__ C0,
           const bf16* __restrict__ A1, const bf16* __restrict__ B1,
           const float* __restrict__ bias1, void* __restrict__ C1,
           int nbm, int nbn, int K, int ldc)
{
    __shared__ __align__(16) char smem[131072];   // 2 x 64KB
    const int tid  = threadIdx.x;
    const int lane = tid & 63;
    const int wid  = tid >> 6;
    const int wm = wid >> 2, wn = wid & 3;
    const int r16 = lane & 15, kb = lane >> 4;

    int bid = blockIdx.x;
    {   // bijective XCD swizzle (m204)
        int nwg = gridDim.x;
        int q = nwg >> 3, r = nwg & 7;
        int xcd = bid & 7, idx = bid >> 3;
        bid = (xcd < r ? xcd * (q + 1) : r * (q + 1) + (xcd - r) * q) + idx;
    }
    const int npg = nbm * nbn;
    const int g   = bid / npg;
    const int lb  = bid - g * npg;
    const int bm = lb / nbn, bn = lb - bm * nbn;

    const bf16*  A    = g ? A1 : A0;
    const bf16*  Bw   = g ? B1 : B0;
    const float* bias = g ? bias1 : bias0;
    char* Cout = (char*)(g ? C1 : C0);

    const long row0 = (long)bm * 256;
    const int  col0 = bn * 256;
    const int  nt   = K >> 6;

    // staging sources (pre-swizzled; involution) + linear LDS dest offset
    const char* gA[2]; const char* gB[2];
    #pragma unroll
    for (int l = 0; l < 2; ++l) {
        const uint32_t S = (uint32_t)(l * 512 + tid) * 16;   // byte slot in 16KB plane
        const int r  = (int)(S >> 6);                        // plane row 0..255
        const int cb = (int)((S & 63) ^ ((uint32_t)((r >> 1) & 3) << 4));
        gA[l] = (const char*)A  + (row0 + r) * (long)K * 2 + cb;
        gB[l] = (const char*)Bw + (long)(col0 + r) * K * 2 + cb;
    }
    const uint32_t ldst = (uint32_t)(tid & ~63) * 16;        // + l*8192 + plane base

    // per-lane read base offsets within a plane (swizzled; proven zero-conflict)
    const uint32_t swz  = ((uint32_t)(r16 >> 1) & 3u) << 4;
    const uint32_t aoff = (uint32_t)((wm * 128 + r16) * 64 + kb * 16) ^ swz;  // + fi*1024 (fi 0..7)
    const uint32_t boff = (uint32_t)((wn * 64  + r16) * 64 + kb * 16) ^ swz;  // + fj*1024 (fj 0..3)

    f32x4 acc[8][4];
    #pragma unroll
    for (int i = 0; i < 8; ++i)
        #pragma unroll
        for (int j = 0; j < 4; ++j)
            acc[i][j] = (f32x4){0.f, 0.f, 0.f, 0.f};

    // stage one kk-plane-pair (A and B) of 4 loads
#define STAGEK(BUFOFF, KOFF)                                                             \
    __builtin_amdgcn_global_load_lds(AS1(gA[0] + (KOFF)), AS3(smem + (BUFOFF) +     0 + ldst), 16, 0, 0); \
    __builtin_amdgcn_global_load_lds(AS1(gA[1] + (KOFF)), AS3(smem + (BUFOFF) +  8192 + ldst), 16, 0, 0); \
    __builtin_amdgcn_global_load_lds(AS1(gB[0] + (KOFF)), AS3(smem + (BUFOFF) + 32768 + ldst), 16, 0, 0); \
    __builtin_amdgcn_global_load_lds(AS1(gB[1] + (KOFF)), AS3(smem + (BUFOFF) + 40960 + ldst), 16, 0, 0);

#define READS(AF, BV, PB, PLOFF)                                                         \
    _Pragma("unroll")                                                                    \
    for (int fi = 0; fi < 8; ++fi) AF[fi] = *(const bf16x8*)((PB) + (PLOFF) + aoff + fi * 1024); \
    _Pragma("unroll")                                                                    \
    for (int fj = 0; fj < 4; ++fj) BV[fj] = *(const bf16x8*)((PB) + (PLOFF) + 32768 + boff + fj * 1024);

#define MFMA32(AF, BV)                                                                   \
    __builtin_amdgcn_s_setprio(1);                                                       \
    _Pragma("unroll")                                                                    \
    for (int fi = 0; fi < 8; ++fi) {                                                     \
        _Pragma("unroll")                                                                \
        for (int fj = 0; fj < 4; ++fj)                                                   \
            acc[fi][fj] = __builtin_amdgcn_mfma_f32_16x16x32_bf16(AF[fi], BV[fj], acc[fi][fj], 0, 0, 0); \
    }                                                                                    \
    __builtin_amdgcn_s_setprio(0);

    // prologue: stage tile0 kk0 then kk1; gate kk0; read set0 = kk0(t0)
    STAGEK(0, 0)
    STAGEK(16384, 64)
    asm volatile("s_waitcnt vmcnt(4)\n\ts_barrier" ::: "memory");

    bf16x8 af0[8], bv0[4], af1[8], bv1[4];
    READS(af0, bv0, smem, 0)

    for (int t = 0; t < nt; ++t) {
        const uint32_t bo  = ((uint32_t)(t & 1)) << 16;
        const uint32_t bo1 = bo ^ 65536u;
        const char* pb = smem + bo;
        const char* pt = smem + bo1;
        const bool  st = (t + 1 < nt);
        const long  k1 = (long)(t + 1) * 128;

        // ---- P0: compute kk0 (set0); read kk1(t) into set1; stage kk0(t+1)
        if (st) { STAGEK(bo1, k1) }
        if (st) asm volatile("s_waitcnt vmcnt(4)" ::: "memory");
        else    asm volatile("s_waitcnt vmcnt(0)" ::: "memory");
        asm volatile("s_barrier" ::: "memory");
        READS(af1, bv1, pb, 16384)
        MFMA32(af0, bv0)

        // ---- P1: compute kk1 (set1); read kk0(t+1) into set0; stage kk1(t+1)
        if (st) {
            STAGEK(bo1 + 16384, k1 + 64)
            asm volatile("s_waitcnt vmcnt(4)" ::: "memory");
        }
        asm volatile("s_barrier" ::: "memory");
        if (st) { READS(af0, bv0, pt, 0) }
        MFMA32(af1, bv1)
    }
#undef MFMA32
#undef READS
#undef STAGEK

    // epilogue: row = row0 + wm*128 + i*16 + (lane>>4)*4 + e ; col = col0 + wn*64 + j*16 + r16
    const int rb = (lane >> 4) * 4;
    #pragma unroll
    for (int i = 0; i < 8; ++i) {
        #pragma unroll
        for (int j = 0; j < 4; ++j) {
            const int cc = col0 + wn * 64 + j * 16 + r16;
            float badd = 0.f;
            if (MODE == 1) badd = bias[cc];
            #pragma unroll
            for (int e = 0; e < 4; ++e) {
                long row = row0 + wm * 128 + i * 16 + rb + e;
                float v = acc[i][j][e];
                if (MODE == 1) {
                    v += badd;
                    v = fmaxf(v, 0.f);
                    v = v * v;
                    ((bf16*)Cout)[row * ldc + cc] = __float2bfloat16(v);
                } else {
                    ((float*)Cout)[row * ldc + cc] = v;
                }
            }
        }
    }
}

// ---------------- glue: per-token gating / tiny einsums ----------------
// In:  g1,g2 [TOK][8][512] f32; Yl[:,0:4096]=x1 raw bf16; Yr[:,4096:8192]=x2 raw bf16
// Out: Yl = [x1*g1s | y12 | g1s]; Yr = [y21 | x2*g2s | g2s]  (all bf16)
#define GPAD 524   // 8-row pad: h-stride hits 8 distinct banks; 524*4%16==0
__global__ __launch_bounds__(256)
void glue(const float* __restrict__ g1, const float* __restrict__ g2,
          bf16* __restrict__ Yl, bf16* __restrict__ Yr)
{
    __shared__ __align__(16) float g1t[8 * GPAD];
    __shared__ __align__(16) float g2t[8 * GPAD];
    __shared__ float g1s[EE], g2s[EE];
    __shared__ float t1s[64], t2s[64];
    __shared__ float t1p[4][64], t2p[4][64];
    __shared__ __align__(16) bf16 x1t[FF], x2t[FF];

    const int t   = blockIdx.x;
    const int tid = threadIdx.x;
    const float* g1p = g1 + (size_t)t * FF;
    const float* g2p = g2 + (size_t)t * FF;
    bf16* ylp = Yl + (size_t)t * KCAT;
    bf16* yrp = Yr + (size_t)t * KCAT;

    #pragma unroll
    for (int c = 0; c < 4; ++c) {
        int idx4 = (c * 256 + tid) * 4;
        float4 v1 = *(const float4*)(g1p + idx4);
        float4 v2 = *(const float4*)(g2p + idx4);
        int h = idx4 >> 9, e = idx4 & 511;
        *(float4*)&g1t[h * GPAD + e] = v1;
        *(float4*)&g2t[h * GPAD + e] = v2;
    }
    #pragma unroll
    for (int c = 0; c < 2; ++c) {
        int idx8 = (c * 256 + tid) * 8;
        *(bf16x8*)&x1t[idx8] = *(const bf16x8*)(ylp + idx8);
        *(bf16x8*)&x2t[idx8] = *(const bf16x8*)(yrp + FF + idx8);
    }
    __syncthreads();

    #pragma unroll
    for (int c = 0; c < 2; ++c) {
        int e = c * 256 + tid;
        float s1 = 0.f, s2 = 0.f;
        #pragma unroll
        for (int h = 0; h < 8; ++h) { s1 += g1t[h * GPAD + e]; s2 += g2t[h * GPAD + e]; }
        g1s[e] = s1; g2s[e] = s2;
    }

    {   // t1[h,m] = sum_e x1[e,m]*g1[h,e] ; t2 likewise. 4-way partials.
        int o = tid & 63;
        int h = o & 7, m = o >> 3;
        int p = tid >> 6;
        float s1 = 0.f, s2 = 0.f;
        #pragma unroll 8
        for (int ii = 0; ii < 128; ++ii) {
            int e = p * 128 + ii;
            float xv1 = __bfloat162float(x1t[e * 8 + m]);
            float xv2 = __bfloat162float(x2t[e * 8 + m]);
            s1 += xv1 * g1t[h * GPAD + e];
            s2 += xv2 * g2t[h * GPAD + e];
        }
        t1p[p][o] = s1; t2p[p][o] = s2;
    }
    __syncthreads();
    if (tid < 64)       t1s[tid] = t1p[0][tid] + t1p[1][tid] + t1p[2][tid] + t1p[3][tid];
    else if (tid < 128) { int o = tid - 64; t2s[o] = t2p[0][o] + t2p[1][o] + t2p[2][o] + t2p[3][o]; }
    __syncthreads();

    #pragma unroll
    for (int c = 0; c < 2; ++c) {
        int f0 = (c * 256 + tid) * 8;
        int e  = f0 >> 3;
        float s1 = g1s[e], s2 = g2s[e];
        bf16x8 xa = *(const bf16x8*)&x1t[f0];
        bf16x8 xb = *(const bf16x8*)&x2t[f0];
        bf16x8 o1, o2;
        #pragma unroll
        for (int u = 0; u < 8; ++u) {
            o1[u] = (__bf16)((float)xa[u] * s1);
            o2[u] = (__bf16)((float)xb[u] * s2);
        }
        *(bf16x8*)(ylp + f0)      = o1;
        *(bf16x8*)(yrp + FF + f0) = o2;
    }
    #pragma unroll
    for (int c = 0; c < 2; ++c) {
        int f0 = (c * 256 + tid) * 8;
        int i  = f0 >> 3;
        bf16x8 o12v, o21v;
        #pragma unroll
        for (int m = 0; m < 8; ++m) {
            float s12 = 0.f, s21 = 0.f;
            #pragma unroll
            for (int h = 0; h < 8; ++h) {
                s12 += t2s[(m << 3) | h] * g1t[h * GPAD + i];
                s21 += t1s[(m << 3) | h] * g2t[h * GPAD + i];
            }
            o12v[m] = (__bf16)s12;
            o21v[m] = (__bf16)s21;
        }
        *(bf16x8*)(ylp + FF + f0) = o12v;
        *(bf16x8*)(yrp + f0)      = o21v;
    }
    {
        int e0 = tid * 2;
        ylp[2 * FF + e0]     = __float2bfloat16(g1s[e0]);
        ylp[2 * FF + e0 + 1] = __float2bfloat16(g1s[e0 + 1]);
        yrp[2 * FF + e0]     = __float2bfloat16(g2s[e0]);
        yrp[2 * FF + e0 + 1] = __float2bfloat16(g2s[e0 + 1]);
    }
}

// ---------------- launch ----------------

extern "C" void kernel_launch(void* const* d_in, const int* in_sizes, int n_in,
                              void* d_out, int out_size, void* d_ws, size_t ws_size,
                              hipStream_t stream) {
    const float* x    = (const float*)d_in[0];
    const float* g1   = (const float*)d_in[1];
    const float* g2   = (const float*)d_in[2];
    const float* u1_w = (const float*)d_in[3];
    const float* u1_b = (const float*)d_in[4];
    const float* u2_w = (const float*)d_in[5];
    const float* u2_b = (const float*)d_in[6];
    const float* v11  = (const float*)d_in[7];
    const float* v12  = (const float*)d_in[8];
    const float* v21  = (const float*)d_in[9];
    const float* v22  = (const float*)d_in[10];
    const float* b1   = (const float*)d_in[11];
    const float* b2   = (const float*)d_in[12];
    float* out = (float*)d_out;

    size_t off = 0;
    char* base = (char*)d_ws;
    auto take = [&](size_t bytes) { void* p = base + off; off += (bytes + 255) & ~(size_t)255; return p; };
    bf16* Xb  = (bf16*)take((size_t)TOK * DD * 2);
    bf16* U1b = (bf16*)take((size_t)FF * DD * 2);
    bf16* U2b = (bf16*)take((size_t)FF * DD * 2);
    bf16* Wl  = (bf16*)take((size_t)HALF * KCAT * 2);
    bf16* Wr  = (bf16*)take((size_t)HALF * KCAT * 2);
    bf16* Yl  = (bf16*)take((size_t)TOK * KCAT * 2);
    bf16* Yr  = (bf16*)take((size_t)TOK * KCAT * 2);

    // prep
    cvt_bf16<<<4096, 256, 0, stream>>>(x,    Xb,  TOK * DD / 4);
    cvt_bf16<<<2048, 256, 0, stream>>>(u1_w, U1b, FF * DD / 4);
    cvt_bf16<<<2048, 256, 0, stream>>>(u2_w, U2b, FF * DD / 4);
    pack_w<<<HALF, 256, 0, stream>>>(v11, v12, b1, Wl);
    pack_w<<<HALF, 256, 0, stream>>>(v21, v22, b2, Wr);

    // fused U-GEMMs: x1raw -> Yl[:,0:4096], x2raw -> Yr[:,4096:8192]  (relu^2, bf16)
    gemmR<1><<<2 * (TOK / 256) * (FF / 256), 512, 0, stream>>>(
        Xb, U1b, u1_b, Yl,
        Xb, U2b, u2_b, Yr + FF,
        TOK / 256, FF / 256, DD, KCAT);

    // gating / tiny einsums
    glue<<<TOK, 256, 0, stream>>>(g1, g2, Yl, Yr);

    // fused V-GEMMs: out[:,0:1024] = Yl @ Wl^T ; out[:,1024:2048] = Yr @ Wr^T  (fp32)
    gemmR<0><<<2 * (TOK / 256) * (HALF / 256), 512, 0, stream>>>(
        Yl, Wl, nullptr, out,
        Yr, Wr, nullptr, out + HALF,
        TOK / 256, HALF / 256, KCAT, DD);
}